// Round 4
// baseline (183.295 us; speedup 1.0000x reference)
//
#include <hip/hip_runtime.h>
#include <hip/hip_cooperative_groups.h>

// loss = BCE_with_logits(pred, psi) + 10 * mean_valid((d_i - d_j)^2)
// d = pred - logit(clamp(psi, eps, 1-eps)), valid = |psi_i - psi_j| >= 0.05.
// N = 8192, output: 1 fp32 scalar.
//
// R4: (a) triangle-only pairs (symmetric matrix, diagonal always invalid;
// mean uses s/c so the x2 cancels) via uniform predicate base+k>tid that is
// auto-true on strictly-upper tiles; (b) single cooperative kernel --
// partials -> grid.sync() -> block 0 reduces (removes finalize launch+gap).

namespace cg = cooperative_groups;

constexpr float DPSI_T    = 0.05f;
constexpr float LOGIT_EPS = 1e-7f;
constexpr int   CB  = 128;   // cols per tile
constexpr int   RB  = 256;   // rows per tile (= TPB)
constexpr int   TPB = 256;
constexpr int   NRB = 32;    // 8192 / 256 row-blocks
// triangle tiles: rb in [0,32), cb in [2rb, 64); off(rb) = rb*(65-rb); total 1056
constexpr int   NTILES = 1056;

__device__ __forceinline__ float logit_f(float p) {
    p = fminf(fmaxf(p, LOGIT_EPS), 1.0f - LOGIT_EPS);
    return logf(p) - log1pf(-p);
}

__device__ __forceinline__ int tri_off(int rb) { return rb * (65 - rb); }

__global__ __launch_bounds__(256) void fused_kernel(const float* __restrict__ pred,
                                                    const float* __restrict__ psi,
                                                    const int* __restrict__ flag,
                                                    float* __restrict__ part_sum,
                                                    unsigned int* __restrict__ part_cnt,
                                                    float* __restrict__ part_bce,
                                                    float* __restrict__ out,
                                                    int n) {
    __shared__ float2 tile[CB];
    const int tid = threadIdx.x;
    const int t   = blockIdx.x;
    const float NANF = __int_as_float(0x7fc00000);

    // Invert t -> (rb, cb) in the upper-triangle tile enumeration.
    int rb = (int)((65.0f - sqrtf(4225.0f - 4.0f * (float)t)) * 0.5f);
    rb = max(0, min(NRB - 1, rb));
    while (rb + 1 < NRB && tri_off(rb + 1) <= t) ++rb;
    while (rb > 0 && tri_off(rb) > t) --rb;
    const int cb = 2 * rb + (t - tri_off(rb));

    // Stage column tile (psi_j, d_j). NaN psi for OOB -> compare always false.
    if (tid < CB) {
        int j = cb * CB + tid;
        if (j < n) {
            float pj = psi[j];
            tile[tid] = make_float2(pj, pred[j] - logit_f(pj));
        } else {
            tile[tid] = make_float2(NANF, 0.0f);
        }
    }

    // BCE slice: blocks 0..1023 cover 8 elements each (1024*8 = 8192).
    float bce = 0.0f;
    if (tid < 8) {
        int i = t * 8 + tid;
        if (t < 1024 && i < n) {
            float x = pred[i], tt = psi[i];
            bce = fmaxf(x, 0.0f) - x * tt + log1pf(expf(-fabsf(x)));
        }
    }

    // Row element.
    float psi_i, d_i;
    {
        int i = rb * RB + tid;
        if (i < n) {
            float pi = psi[i];
            psi_i = pi;
            d_i   = pred[i] - logit_f(pi);
        } else {
            psi_i = NANF;
            d_i   = 0.0f;
        }
    }
    __syncthreads();

    // Upper-triangle predicate: j > i  <=>  base + k > tid, base uniform.
    // For strictly-upper tiles (cb >= 2rb+2) base >= 256 > tid: always true.
    const int base = cb * CB - rb * RB;

    float sum = 0.0f;
    unsigned int cntw = 0;   // wave-uniform count via ballot/popcount
    #pragma unroll 8
    for (int k = 0; k < CB; ++k) {
        float2 tc = tile[k];   // broadcast read (conflict-free)
        float dpsi = psi_i - tc.x;
        bool  v    = (fabsf(dpsi) >= DPSI_T) && (base + k > tid);  // NaN -> false
        float dd   = d_i - tc.y;
        float ddm  = v ? dd : 0.0f;
        sum = fmaf(ddm, ddm, sum);
        cntw += (unsigned int)__popcll(__ballot(v));
    }

    for (int off = 32; off; off >>= 1) {
        sum += __shfl_down(sum, off);
        bce += __shfl_down(bce, off);   // lanes >= 8 contribute 0
    }

    __shared__ float wsum[4];
    __shared__ unsigned int wcnt[4];
    int wave = tid >> 6, lane = tid & 63;
    if (lane == 0) { wsum[wave] = sum; wcnt[wave] = cntw; }
    __syncthreads();
    if (tid == 0) {
        part_sum[t] = (wsum[0] + wsum[1]) + (wsum[2] + wsum[3]);
        part_cnt[t] = wcnt[0] + wcnt[1] + wcnt[2] + wcnt[3];
        part_bce[t] = bce;   // wave-0 reduced
    }
    __threadfence();

    cg::this_grid().sync();

    // Block 0 reduces the 1056 partials and finalizes.
    if (blockIdx.x == 0) {
        float s = 0.0f, b = 0.0f;
        unsigned long long c = 0;
        for (int p = tid; p < NTILES; p += TPB) {
            s += part_sum[p];
            b += part_bce[p];
            c += (unsigned long long)part_cnt[p];
        }
        for (int off = 32; off; off >>= 1) {
            s += __shfl_down(s, off);
            b += __shfl_down(b, off);
            c += __shfl_down(c, off);
        }
        __shared__ float s4[4], b4[4];
        __shared__ unsigned long long c4[4];
        if (lane == 0) { s4[wave] = s; b4[wave] = b; c4[wave] = c; }
        __syncthreads();
        if (tid == 0) {
            float s_total = (s4[0] + s4[1]) + (s4[2] + s4[3]);
            float b_total = (b4[0] + b4[1]) + (b4[2] + b4[3]);
            unsigned long long c_total = c4[0] + c4[1] + c4[2] + c4[3];
            float loss = b_total / (float)n;
            // upper-triangle sum/count: mean = (2s)/(2c) = s/c; c>0 <=> 2c>0.
            if (flag[0] == 0 && c_total > 0) {
                loss += 10.0f * (s_total / (float)c_total);
            }
            out[0] = loss;
        }
    }
}

extern "C" void kernel_launch(void* const* d_in, const int* in_sizes, int n_in,
                              void* d_out, int out_size, void* d_ws, size_t ws_size,
                              hipStream_t stream) {
    const float* pred = (const float*)d_in[0];
    const float* psi  = (const float*)d_in[1];
    const int*   flag = (const int*)d_in[2];
    float* out = (float*)d_out;
    int n = in_sizes[0];

    float* part_sum        = (float*)d_ws;
    unsigned int* part_cnt = (unsigned int*)((char*)d_ws + (size_t)NTILES * sizeof(float));
    float* part_bce        = (float*)((char*)d_ws + (size_t)2 * NTILES * sizeof(float));

    void* args[] = {(void*)&pred, (void*)&psi, (void*)&flag, (void*)&part_sum,
                    (void*)&part_cnt, (void*)&part_bce, (void*)&out, (void*)&n};
    hipLaunchCooperativeKernel((const void*)fused_kernel, dim3(NTILES), dim3(TPB),
                               args, 0, stream);
}

// Round 5
// 68.449 us; speedup vs baseline: 2.6778x; 2.6778x over previous
//
#include <hip/hip_runtime.h>

// loss = BCE_with_logits(pred, psi) + 10 * mean_valid((d_i - d_j)^2)
// d = pred - logit(clamp(psi, eps, 1-eps)), valid = |psi_i - psi_j| >= 0.05.
// N = 8192, output: 1 fp32 scalar.
//
// R5: R3's two-kernel structure (coop grid.sync in R4 cost ~110us -- dead end)
// + R4's validated triangle enumeration (j>i only; mean = s/c, the x2 from
// symmetry cancels; diagonal always invalid). 992/1056 tiles are strictly
// upper -> predicate-free 5-VALU inner loop via wave-uniform branch.

constexpr float DPSI_T    = 0.05f;
constexpr float LOGIT_EPS = 1e-7f;
constexpr int   CB  = 128;   // cols per tile
constexpr int   RB  = 256;   // rows per tile (= TPB)
constexpr int   TPB = 256;
constexpr int   NRB = 32;    // 8192/256 row-blocks
// triangle tiles: rb in [0,32), cb in [2rb, 64); off(rb) = rb*(65-rb); total 1056
constexpr int   NTILES = 1056;

__device__ __forceinline__ float logit_f(float p) {
    p = fminf(fmaxf(p, LOGIT_EPS), 1.0f - LOGIT_EPS);
    return logf(p) - log1pf(-p);
}

__device__ __forceinline__ int tri_off(int rb) { return rb * (65 - rb); }

__global__ __launch_bounds__(256) void pair_kernel(const float* __restrict__ pred,
                                                   const float* __restrict__ psi,
                                                   float* __restrict__ part_sum,
                                                   unsigned int* __restrict__ part_cnt,
                                                   float* __restrict__ part_bce,
                                                   int n) {
    __shared__ float2 tile[CB];
    const int tid = threadIdx.x;
    const int t   = blockIdx.x;
    const float NANF = __int_as_float(0x7fc00000);

    // Invert t -> (rb, cb) in the upper-triangle tile enumeration (validated R4).
    int rb = (int)((65.0f - sqrtf(4225.0f - 4.0f * (float)t)) * 0.5f);
    rb = max(0, min(NRB - 1, rb));
    while (rb + 1 < NRB && tri_off(rb + 1) <= t) ++rb;
    while (rb > 0 && tri_off(rb) > t) --rb;
    const int cb = 2 * rb + (t - tri_off(rb));

    // Stage column tile (psi_j, d_j). NaN psi for OOB -> compare always false.
    if (tid < CB) {
        int j = cb * CB + tid;
        if (j < n) {
            float pj = psi[j];
            tile[tid] = make_float2(pj, pred[j] - logit_f(pj));
        } else {
            tile[tid] = make_float2(NANF, 0.0f);
        }
    }

    // BCE slice: blocks 0..1023 cover 8 elements each (1024*8 = 8192).
    float bce = 0.0f;
    if (tid < 8) {
        int i = t * 8 + tid;
        if (t < 1024 && i < n) {
            float x = pred[i], tt = psi[i];
            bce = fmaxf(x, 0.0f) - x * tt + log1pf(expf(-fabsf(x)));
        }
    }

    // Row element.
    float psi_i, d_i;
    {
        int i = rb * RB + tid;
        if (i < n) {
            float pi = psi[i];
            psi_i = pi;
            d_i   = pred[i] - logit_f(pi);
        } else {
            psi_i = NANF;
            d_i   = 0.0f;
        }
    }
    __syncthreads();

    // j > i  <=>  base + k > tid with wave-uniform base = cb*CB - rb*RB.
    // Strictly-upper tiles (base >= TPB): predicate always true -> free loop.
    const int base = cb * CB - rb * RB;

    float sum = 0.0f;
    unsigned int cntw = 0;   // wave-uniform count via ballot/popcount (scalar pipe)
    if (base >= TPB) {
        #pragma unroll 8
        for (int k = 0; k < CB; ++k) {
            float2 tc = tile[k];                      // LDS broadcast read
            float dpsi = psi_i - tc.x;
            bool  v    = fabsf(dpsi) >= DPSI_T;       // NaN -> false
            float dd   = d_i - tc.y;
            float ddm  = v ? dd : 0.0f;
            sum = fmaf(ddm, ddm, sum);
            cntw += (unsigned int)__popcll(__ballot(v));
        }
    } else {
        #pragma unroll 8
        for (int k = 0; k < CB; ++k) {
            float2 tc = tile[k];
            float dpsi = psi_i - tc.x;
            bool  v    = (fabsf(dpsi) >= DPSI_T) && (base + k > tid);
            float dd   = d_i - tc.y;
            float ddm  = v ? dd : 0.0f;
            sum = fmaf(ddm, ddm, sum);
            cntw += (unsigned int)__popcll(__ballot(v));
        }
    }

    for (int off = 32; off; off >>= 1) {
        sum += __shfl_down(sum, off);
        bce += __shfl_down(bce, off);   // lanes >= 8 contribute 0
    }

    __shared__ float wsum[4];
    __shared__ unsigned int wcnt[4];
    int wave = tid >> 6, lane = tid & 63;
    if (lane == 0) { wsum[wave] = sum; wcnt[wave] = cntw; }
    __syncthreads();
    if (tid == 0) {
        part_sum[t] = (wsum[0] + wsum[1]) + (wsum[2] + wsum[3]);
        part_cnt[t] = wcnt[0] + wcnt[1] + wcnt[2] + wcnt[3];
        part_bce[t] = bce;   // wave-0 reduced
    }
}

// One block: reduce NTILES per-block partials + finalize.
__global__ __launch_bounds__(256) void finalize_kernel(const int* __restrict__ flag,
                                                       const float* __restrict__ part_sum,
                                                       const unsigned int* __restrict__ part_cnt,
                                                       const float* __restrict__ part_bce,
                                                       float* __restrict__ out,
                                                       int n) {
    const int tid = threadIdx.x;

    float s = 0.0f, b = 0.0f;
    unsigned long long c = 0;
    for (int p = tid; p < NTILES; p += TPB) {
        s += part_sum[p];
        b += part_bce[p];
        c += (unsigned long long)part_cnt[p];
    }

    for (int off = 32; off; off >>= 1) {
        s += __shfl_down(s, off);
        b += __shfl_down(b, off);
        c += __shfl_down(c, off);
    }
    __shared__ float s4[4], b4[4];
    __shared__ unsigned long long c4[4];
    int wave = tid >> 6, lane = tid & 63;
    if (lane == 0) { s4[wave] = s; b4[wave] = b; c4[wave] = c; }
    __syncthreads();
    if (tid == 0) {
        float s_total = (s4[0] + s4[1]) + (s4[2] + s4[3]);
        float b_total = (b4[0] + b4[1]) + (b4[2] + b4[3]);
        unsigned long long c_total = c4[0] + c4[1] + c4[2] + c4[3];
        float loss = b_total / (float)n;
        // upper-triangle sums: mean = (2s)/(2c) = s/c; c>0 <=> full count>0.
        if (flag[0] == 0 && c_total > 0) {
            loss += 10.0f * (s_total / (float)c_total);
        }
        out[0] = loss;
    }
}

extern "C" void kernel_launch(void* const* d_in, const int* in_sizes, int n_in,
                              void* d_out, int out_size, void* d_ws, size_t ws_size,
                              hipStream_t stream) {
    const float* pred = (const float*)d_in[0];
    const float* psi  = (const float*)d_in[1];
    const int*   flag = (const int*)d_in[2];
    float* out = (float*)d_out;
    int n = in_sizes[0];

    float* part_sum        = (float*)d_ws;
    unsigned int* part_cnt = (unsigned int*)((char*)d_ws + (size_t)NTILES * sizeof(float));
    float* part_bce        = (float*)((char*)d_ws + (size_t)2 * NTILES * sizeof(float));

    pair_kernel<<<NTILES, TPB, 0, stream>>>(pred, psi, part_sum, part_cnt, part_bce, n);
    finalize_kernel<<<1, TPB, 0, stream>>>(flag, part_sum, part_cnt, part_bce, out, n);
}